// Round 1
// baseline (205.772 us; speedup 1.0000x reference)
//
#include <hip/hip_runtime.h>
#include <hip/hip_fp16.h>

#define P_PLANE (1080*1920)          // 2,073,600 pixels per channel plane
#define LUT_C   35937                 // 33*33*33, per-channel LUT stride
#define N_IMG   4
#define SMEM_WORDS 35937
#define SMEM_BYTES (SMEM_WORDS * 4)   // 143,748 B of LDS

#define PPI         (P_PLANE / 8)     // 259,200 8-pixel groups per image
#define TOTAL_PAIRS (N_IMG * PPI)     // 1,036,800

typedef float fvec4 __attribute__((ext_vector_type(4)));   // builtin-compatible float4

// ---------------------------------------------------------------------------
// Build linear u8 table in ws: entry i (= b*1089+g*33+r) packs (r,g,b,0) u8.
// 35937 entries * 4B = 140.4 KB. Quantization err <= 1/510 ~ 2e-3.
// ---------------------------------------------------------------------------
__global__ __launch_bounds__(256) void build_lin_u8(const float* __restrict__ lut,
                                                    unsigned int* __restrict__ T) {
    int i = blockIdx.x * blockDim.x + threadIdx.x;
    if (i >= LUT_C) return;
    unsigned int r = (unsigned int)__float2int_rn(lut[i] * 255.0f);
    unsigned int g = (unsigned int)__float2int_rn(lut[LUT_C + i] * 255.0f);
    unsigned int b = (unsigned int)__float2int_rn(lut[2 * LUT_C + i] * 255.0f);
    T[i] = r | (g << 8) | (b << 16);
}

__device__ __forceinline__ float ub0(unsigned int e) { return (float)(e & 255u); }
__device__ __forceinline__ float ub1(unsigned int e) { return (float)((e >> 8) & 255u); }
__device__ __forceinline__ float ub2(unsigned int e) { return (float)((e >> 16) & 255u); }

// ---------------------------------------------------------------------------
// Main kernel: full LUT (u8x4) resident in LDS.
// ILP restructure vs previous version:
//   - 8 pixels (two float4 quads, 32B contiguous) per thread per iteration
//   - phase-batched: all idx calc -> all 64 LDS gathers -> all FMAs
//   - software-pipelined global loads: next iteration's 6 dwordx4 loads are
//     issued before the current iteration's LDS results are consumed
//   - __launch_bounds__(1024,4): occupancy is LDS-capped at 4 waves/SIMD
//     anyway (143.7 KB -> 1 block/CU); grant the full 128-VGPR budget so the
//     scheduler hoists loads instead of serializing (prev version: 40 VGPR).
// ---------------------------------------------------------------------------
__global__ __launch_bounds__(1024, 4) void apply_lut_lds(const float* __restrict__ x,
                                                         const unsigned int* __restrict__ T,
                                                         float* __restrict__ out) {
    extern __shared__ unsigned int s_lut[];
    const int tid = threadIdx.x;

    // Fill LDS: 8984 uint4 + 1 tail word, coalesced.
    {
        const uint4* Tv = (const uint4*)T;
        uint4* sv = (uint4*)s_lut;
        for (int i = tid; i < SMEM_WORDS / 4; i += blockDim.x) sv[i] = Tv[i];
        if (tid == 0) s_lut[SMEM_WORDS - 1] = T[SMEM_WORDS - 1];
    }
    __syncthreads();

    const float inv = (float)(1.0 / (1.000001 / 32.0));   // matches reference f32 rounding
    const float qs = 1.0f / 255.0f;                        // u8 dequant, folded into wb
    const int stride = gridDim.x * blockDim.x;

    int p = blockIdx.x * blockDim.x + tid;
    if (p >= TOTAL_PAIRS) return;

    size_t base;
    {
        int n = p / PPI;
        base = (size_t)n * (3 * P_PLANE) + (size_t)(p - n * PPI) * 8;
    }
    fvec4 rA = *(const fvec4*)(x + base);
    fvec4 rB = *(const fvec4*)(x + base + 4);
    fvec4 gA = *(const fvec4*)(x + base + P_PLANE);
    fvec4 gB = *(const fvec4*)(x + base + P_PLANE + 4);
    fvec4 bA = *(const fvec4*)(x + base + 2 * P_PLANE);
    fvec4 bB = *(const fvec4*)(x + base + 2 * P_PLANE + 4);

    while (true) {
        // ---- Phase 0: issue next iteration's global loads ASAP (longest latency).
        // Branchless: clamp to current p on the last iteration (L1-hot re-read).
        int pn = p + stride;
        int pc = (pn < TOTAL_PAIRS) ? pn : p;
        size_t nbase;
        {
            int n = pc / PPI;
            nbase = (size_t)n * (3 * P_PLANE) + (size_t)(pc - n * PPI) * 8;
        }
        fvec4 nrA = *(const fvec4*)(x + nbase);
        fvec4 nrB = *(const fvec4*)(x + nbase + 4);
        fvec4 ngA = *(const fvec4*)(x + nbase + P_PLANE);
        fvec4 ngB = *(const fvec4*)(x + nbase + P_PLANE + 4);
        fvec4 nbA = *(const fvec4*)(x + nbase + 2 * P_PLANE);
        fvec4 nbB = *(const fvec4*)(x + nbase + 2 * P_PLANE + 4);

        // ---- Phase 1: indices + fracs for all 8 pixels (x regs die here).
        int   idx[8];
        float fr[8], fg[8], fb[8];
#pragma unroll
        for (int j = 0; j < 8; ++j) {
            float r = (j < 4) ? rA[j] : rB[j - 4];
            float g = (j < 4) ? gA[j] : gB[j - 4];
            float b = (j < 4) ? bA[j] : bB[j - 4];
            float tr = r * inv, tg = g * inv, tb = b * inv;
            float fr_ = floorf(tr), fg_ = floorf(tg), fb_ = floorf(tb);
            fr[j] = tr - fr_; fg[j] = tg - fg_; fb[j] = tb - fb_;   // fracs BEFORE clip
            int ri = min(max((int)fr_, 0), 31);
            int gi = min(max((int)fg_, 0), 31);
            int bi = min(max((int)fb_, 0), 31);
            idx[j] = bi * 1089 + gi * 33 + ri;
        }

        // ---- Phase 2: all 64 LDS gathers in flight (fuses to ds_read2_b32 pairs).
        unsigned int e[8][8];
#pragma unroll
        for (int j = 0; j < 8; ++j) {
            int i0 = idx[j];
            int i1 = idx[j] + 1089;
            e[j][0] = s_lut[i0];       e[j][1] = s_lut[i0 + 1];
            e[j][2] = s_lut[i0 + 33];  e[j][3] = s_lut[i0 + 34];
            e[j][4] = s_lut[i1];       e[j][5] = s_lut[i1 + 1];
            e[j][6] = s_lut[i1 + 33];  e[j][7] = s_lut[i1 + 34];
        }

        // ---- Phase 3: interpolate all 8 pixels.
        fvec4 oRA, oRB, oGA, oGB, oBA, oBB;
#pragma unroll
        for (int j = 0; j < 8; ++j) {
            float wr1 = fr[j], wr0 = 1.0f - fr[j];
            float wg1 = fg[j], wg0 = 1.0f - fg[j];
            float wb1 = fb[j] * qs, wb0 = (1.0f - fb[j]) * qs;   // fold 1/255 here
            float w00 = wb0 * wg0, w01 = wb0 * wg1, w10 = wb1 * wg0, w11 = wb1 * wg1;
            float w000 = w00 * wr0, w001 = w00 * wr1;
            float w010 = w01 * wr0, w011 = w01 * wr1;
            float w100 = w10 * wr0, w101 = w10 * wr1;
            float w110 = w11 * wr0, w111 = w11 * wr1;

            float aR = w000 * ub0(e[j][0]);
            float aG = w000 * ub1(e[j][0]);
            float aB = w000 * ub2(e[j][0]);
            aR = fmaf(w001, ub0(e[j][1]), aR); aG = fmaf(w001, ub1(e[j][1]), aG); aB = fmaf(w001, ub2(e[j][1]), aB);
            aR = fmaf(w010, ub0(e[j][2]), aR); aG = fmaf(w010, ub1(e[j][2]), aG); aB = fmaf(w010, ub2(e[j][2]), aB);
            aR = fmaf(w011, ub0(e[j][3]), aR); aG = fmaf(w011, ub1(e[j][3]), aG); aB = fmaf(w011, ub2(e[j][3]), aB);
            aR = fmaf(w100, ub0(e[j][4]), aR); aG = fmaf(w100, ub1(e[j][4]), aG); aB = fmaf(w100, ub2(e[j][4]), aB);
            aR = fmaf(w101, ub0(e[j][5]), aR); aG = fmaf(w101, ub1(e[j][5]), aG); aB = fmaf(w101, ub2(e[j][5]), aB);
            aR = fmaf(w110, ub0(e[j][6]), aR); aG = fmaf(w110, ub1(e[j][6]), aG); aB = fmaf(w110, ub2(e[j][6]), aB);
            aR = fmaf(w111, ub0(e[j][7]), aR); aG = fmaf(w111, ub1(e[j][7]), aG); aB = fmaf(w111, ub2(e[j][7]), aB);

            if (j < 4) { oRA[j] = aR;     oGA[j] = aG;     oBA[j] = aB; }
            else       { oRB[j - 4] = aR; oGB[j - 4] = aG; oBB[j - 4] = aB; }
        }

        // ---- Phase 4: 6 nontemporal 16B stores (write-once stream).
        __builtin_nontemporal_store(oRA, (fvec4*)(out + base));
        __builtin_nontemporal_store(oRB, (fvec4*)(out + base + 4));
        __builtin_nontemporal_store(oGA, (fvec4*)(out + base + P_PLANE));
        __builtin_nontemporal_store(oGB, (fvec4*)(out + base + P_PLANE + 4));
        __builtin_nontemporal_store(oBA, (fvec4*)(out + base + 2 * P_PLANE));
        __builtin_nontemporal_store(oBB, (fvec4*)(out + base + 2 * P_PLANE + 4));

        if (pn >= TOTAL_PAIRS) break;
        p = pn; base = nbase;
        rA = nrA; rB = nrB; gA = ngA; gB = ngB; bA = nbA; bB = nbB;
    }
}

// ===========================================================================
// Fallback path (R0, proven): fp16 cell-duplicated table + global gathers.
// ===========================================================================
__global__ __launch_bounds__(256) void build_table(const float* __restrict__ lut,
                                                   uint4* __restrict__ T) {
    int cell = blockIdx.x * blockDim.x + threadIdx.x;   // 0 .. 32767
    int rid = cell & 31;
    int gid = (cell >> 5) & 31;
    int bid = cell >> 10;
    const float* b0 = lut + bid * 1089 + gid * 33 + rid;
    uint4 q[4];
    __half* h = (__half*)q;
#pragma unroll
    for (int k = 0; k < 8; ++k) {
        int off = (k >> 2) * 1089 + ((k >> 1) & 1) * 33 + (k & 1);
        h[k * 4 + 0] = __float2half(b0[off]);
        h[k * 4 + 1] = __float2half(b0[LUT_C + off]);
        h[k * 4 + 2] = __float2half(b0[2 * LUT_C + off]);
        h[k * 4 + 3] = __float2half(0.0f);
    }
    uint4* dst = T + (size_t)cell * 4;
    dst[0] = q[0]; dst[1] = q[1]; dst[2] = q[2]; dst[3] = q[3];
}

__device__ __forceinline__ void acc_chunk(const uint4& q, float wA, float wB,
                                          float& aR, float& aG, float& aB) {
    const __half* h = (const __half*)&q;
    aR = fmaf(wA, __half2float(h[0]), fmaf(wB, __half2float(h[4]), aR));
    aG = fmaf(wA, __half2float(h[1]), fmaf(wB, __half2float(h[5]), aG));
    aB = fmaf(wA, __half2float(h[2]), fmaf(wB, __half2float(h[6]), aB));
}

__global__ __launch_bounds__(256) void apply_lut(const float* __restrict__ x,
                                                 const __half* __restrict__ T,
                                                 float* __restrict__ out) {
    const float inv = (float)(1.0 / (1.000001 / 32.0));
    int n  = blockIdx.y;
    int i4 = blockIdx.x * blockDim.x + threadIdx.x;
    size_t base = (size_t)n * 3 * P_PLANE + (size_t)i4 * 4;

    float4 r4 = *(const float4*)(x + base);
    float4 g4 = *(const float4*)(x + base + P_PLANE);
    float4 b4 = *(const float4*)(x + base + 2 * P_PLANE);

    float r[4] = {r4.x, r4.y, r4.z, r4.w};
    float g[4] = {g4.x, g4.y, g4.z, g4.w};
    float b[4] = {b4.x, b4.y, b4.z, b4.w};
    float oR[4], oG[4], oB[4];

#pragma unroll
    for (int i = 0; i < 4; ++i) {
        float tr = r[i] * inv;
        float tg = g[i] * inv;
        float tb = b[i] * inv;
        float fr_ = floorf(tr), fg_ = floorf(tg), fb_ = floorf(tb);
        float fr = tr - fr_, fg = tg - fg_, fb = tb - fb_;
        int ri = min(max((int)fr_, 0), 31);
        int gi = min(max((int)fg_, 0), 31);
        int bi = min(max((int)fb_, 0), 31);

        const uint4* cp = (const uint4*)(T + ((size_t)(((bi << 5) | gi) << 5 | ri) << 5));
        uint4 q0 = cp[0], q1 = cp[1], q2 = cp[2], q3 = cp[3];

        float wr1 = fr, wr0 = 1.0f - fr;
        float wg1 = fg, wg0 = 1.0f - fg;
        float wb1 = fb, wb0 = 1.0f - fb;
        float w00 = wb0 * wg0, w01 = wb0 * wg1, w10 = wb1 * wg0, w11 = wb1 * wg1;

        float aR = 0.f, aG = 0.f, aB = 0.f;
        acc_chunk(q0, w00 * wr0, w00 * wr1, aR, aG, aB);
        acc_chunk(q1, w01 * wr0, w01 * wr1, aR, aG, aB);
        acc_chunk(q2, w10 * wr0, w10 * wr1, aR, aG, aB);
        acc_chunk(q3, w11 * wr0, w11 * wr1, aR, aG, aB);

        oR[i] = aR; oG[i] = aG; oB[i] = aB;
    }

    *(float4*)(out + base)               = make_float4(oR[0], oR[1], oR[2], oR[3]);
    *(float4*)(out + base + P_PLANE)     = make_float4(oG[0], oG[1], oG[2], oG[3]);
    *(float4*)(out + base + 2 * P_PLANE) = make_float4(oB[0], oB[1], oB[2], oB[3]);
}

extern "C" void kernel_launch(void* const* d_in, const int* in_sizes, int n_in,
                              void* d_out, int out_size, void* d_ws, size_t ws_size,
                              hipStream_t stream) {
    const float* lut = (const float*)d_in[0];
    const float* x   = (const float*)d_in[1];
    float* out = (float*)d_out;

    // Capture-safe host-side queries — cached so repeated kernel_launch calls
    // don't pay the runtime-API cost per invocation.
    static int max_shm = -1;
    if (max_shm < 0) {
        int dev = 0;
        (void)hipGetDevice(&dev);
        (void)hipDeviceGetAttribute(&max_shm, hipDeviceAttributeMaxSharedMemoryPerBlock, dev);
        static_assert(SMEM_BYTES == 143748, "lut lds size");
        (void)hipFuncSetAttribute((const void*)apply_lut_lds,
                                  hipFuncAttributeMaxDynamicSharedMemorySize, SMEM_BYTES);
        if (max_shm < 0) max_shm = 0;
    }

    const size_t lin_bytes = (size_t)SMEM_BYTES;
    if (max_shm >= SMEM_BYTES && ws_size >= lin_bytes) {
        unsigned int* T = (unsigned int*)d_ws;
        build_lin_u8<<<(LUT_C + 255) / 256, 256, 0, stream>>>(lut, T);
        // 256 blocks x 1024 threads, 1 block/CU (LDS-bound), grid-stride over
        // 8-pixel groups.
        apply_lut_lds<<<256, 1024, SMEM_BYTES, stream>>>(x, T, out);
    } else {
        __half* T = (__half*)d_ws;
        build_table<<<128, 256, 0, stream>>>(lut, (uint4*)T);
        apply_lut<<<dim3(P_PLANE / (4 * 256), N_IMG), 256, 0, stream>>>(x, T, out);
    }
}

// Round 2
// 185.260 us; speedup vs baseline: 1.1107x; 1.1107x over previous
//
#include <hip/hip_runtime.h>
#include <hip/hip_fp16.h>

#define P_PLANE (1080*1920)          // 2,073,600 pixels per channel plane
#define LUT_C   35937                 // 33*33*33, per-channel LUT stride
#define N_IMG   4
#define SMEM_WORDS 35937
#define SMEM_BYTES (SMEM_WORDS * 4)   // 143,748 B of LDS

typedef float fvec4 __attribute__((ext_vector_type(4)));   // builtin-compatible float4

// ---------------------------------------------------------------------------
// Build linear u8 table in ws: entry i (= b*1089+g*33+r) packs (r,g,b,0) u8.
// 35937 entries * 4B = 140.4 KB. Quantization err <= 1/510 ~ 2e-3.
// ---------------------------------------------------------------------------
__global__ __launch_bounds__(256) void build_lin_u8(const float* __restrict__ lut,
                                                    unsigned int* __restrict__ T) {
    int i = blockIdx.x * blockDim.x + threadIdx.x;
    if (i >= LUT_C) return;
    unsigned int r = (unsigned int)__float2int_rn(lut[i] * 255.0f);
    unsigned int g = (unsigned int)__float2int_rn(lut[LUT_C + i] * 255.0f);
    unsigned int b = (unsigned int)__float2int_rn(lut[2 * LUT_C + i] * 255.0f);
    T[i] = r | (g << 8) | (b << 16);
}

__device__ __forceinline__ float ub0(unsigned int e) { return (float)(e & 255u); }
__device__ __forceinline__ float ub1(unsigned int e) { return (float)((e >> 8) & 255u); }
__device__ __forceinline__ float ub2(unsigned int e) { return (float)((e >> 16) & 255u); }

// ---------------------------------------------------------------------------
// Main kernel: full LUT (u8x4) resident in LDS.
// R2: 8 pixels/thread ILP, but as TWO GRID-SEPARATED quads (q and q+G) so
// every store is a full wave-contiguous 1KB (64 lanes x 16B consecutive) —
// R1's adjacent-8-pixel layout half-covered cachelines and blew WRITE_SIZE
// up 1.6x (97->156 MB). Phase-batched: all idx calc -> all 64 LDS gathers
// (ds_read2_b32 pairs) -> all 192 FMAs, so global+LDS latency overlaps.
// ---------------------------------------------------------------------------
__global__ __launch_bounds__(1024, 4) void apply_lut_lds(const float* __restrict__ x,
                                                         const unsigned int* __restrict__ T,
                                                         float* __restrict__ out) {
    extern __shared__ unsigned int s_lut[];
    const int tid = threadIdx.x;

    // Fill LDS: 8984 uint4 + 1 tail word, coalesced.
    {
        const uint4* Tv = (const uint4*)T;
        uint4* sv = (uint4*)s_lut;
        for (int i = tid; i < SMEM_WORDS / 4; i += blockDim.x) sv[i] = Tv[i];
        if (tid == 0) s_lut[SMEM_WORDS - 1] = T[SMEM_WORDS - 1];
    }
    __syncthreads();

    const float inv = (float)(1.0 / (1.000001 / 32.0));   // matches reference f32 rounding
    const float qs = 1.0f / 255.0f;                        // u8 dequant, folded into wb
    const int QPI = P_PLANE / 4;                           // 518,400 quads per image
    const int total = N_IMG * QPI;                         // 2,073,600 quads
    const int G = gridDim.x * blockDim.x;                  // 262,144

    for (int q0 = blockIdx.x * blockDim.x + tid; q0 < total; q0 += 2 * G) {
        int q1 = q0 + G;
        const bool has2 = (q1 < total);
        int q1c = has2 ? q1 : q0;          // branchless: OOB lanes redo q0 (L1-hot)

        int n0 = q0 / QPI;
        size_t base0 = (size_t)n0 * (3 * P_PLANE) + (size_t)(q0 - n0 * QPI) * 4;
        int n1 = q1c / QPI;
        size_t base1 = (size_t)n1 * (3 * P_PLANE) + (size_t)(q1c - n1 * QPI) * 4;

        // ---- Phase 0: 6 coalesced dwordx4 loads in flight.
        fvec4 rA = *(const fvec4*)(x + base0);
        fvec4 gA = *(const fvec4*)(x + base0 + P_PLANE);
        fvec4 bA = *(const fvec4*)(x + base0 + 2 * P_PLANE);
        fvec4 rB = *(const fvec4*)(x + base1);
        fvec4 gB = *(const fvec4*)(x + base1 + P_PLANE);
        fvec4 bB = *(const fvec4*)(x + base1 + 2 * P_PLANE);

        // ---- Phase 1: indices + fracs for all 8 pixels.
        int   idx[8];
        float fr[8], fg[8], fb[8];
#pragma unroll
        for (int j = 0; j < 8; ++j) {
            float r = (j < 4) ? rA[j] : rB[j - 4];
            float g = (j < 4) ? gA[j] : gB[j - 4];
            float b = (j < 4) ? bA[j] : bB[j - 4];
            float tr = r * inv, tg = g * inv, tb = b * inv;
            float fr_ = floorf(tr), fg_ = floorf(tg), fb_ = floorf(tb);
            fr[j] = tr - fr_; fg[j] = tg - fg_; fb[j] = tb - fb_;   // fracs BEFORE clip
            int ri = min(max((int)fr_, 0), 31);
            int gi = min(max((int)fg_, 0), 31);
            int bi = min(max((int)fb_, 0), 31);
            idx[j] = bi * 1089 + gi * 33 + ri;
        }

        // ---- Phase 2: all 64 LDS gathers in flight (fuses to ds_read2_b32 pairs).
        unsigned int e[8][8];
#pragma unroll
        for (int j = 0; j < 8; ++j) {
            int i0 = idx[j];
            int i1 = idx[j] + 1089;
            e[j][0] = s_lut[i0];       e[j][1] = s_lut[i0 + 1];
            e[j][2] = s_lut[i0 + 33];  e[j][3] = s_lut[i0 + 34];
            e[j][4] = s_lut[i1];       e[j][5] = s_lut[i1 + 1];
            e[j][6] = s_lut[i1 + 33];  e[j][7] = s_lut[i1 + 34];
        }

        // ---- Phase 3: interpolate all 8 pixels.
        fvec4 oRA, oGA, oBA, oRB, oGB, oBB;
#pragma unroll
        for (int j = 0; j < 8; ++j) {
            float wr1 = fr[j], wr0 = 1.0f - fr[j];
            float wg1 = fg[j], wg0 = 1.0f - fg[j];
            float wb1 = fb[j] * qs, wb0 = (1.0f - fb[j]) * qs;   // fold 1/255 here
            float w00 = wb0 * wg0, w01 = wb0 * wg1, w10 = wb1 * wg0, w11 = wb1 * wg1;
            float w000 = w00 * wr0, w001 = w00 * wr1;
            float w010 = w01 * wr0, w011 = w01 * wr1;
            float w100 = w10 * wr0, w101 = w10 * wr1;
            float w110 = w11 * wr0, w111 = w11 * wr1;

            float aR = w000 * ub0(e[j][0]);
            float aG = w000 * ub1(e[j][0]);
            float aB = w000 * ub2(e[j][0]);
            aR = fmaf(w001, ub0(e[j][1]), aR); aG = fmaf(w001, ub1(e[j][1]), aG); aB = fmaf(w001, ub2(e[j][1]), aB);
            aR = fmaf(w010, ub0(e[j][2]), aR); aG = fmaf(w010, ub1(e[j][2]), aG); aB = fmaf(w010, ub2(e[j][2]), aB);
            aR = fmaf(w011, ub0(e[j][3]), aR); aG = fmaf(w011, ub1(e[j][3]), aG); aB = fmaf(w011, ub2(e[j][3]), aB);
            aR = fmaf(w100, ub0(e[j][4]), aR); aG = fmaf(w100, ub1(e[j][4]), aG); aB = fmaf(w100, ub2(e[j][4]), aB);
            aR = fmaf(w101, ub0(e[j][5]), aR); aG = fmaf(w101, ub1(e[j][5]), aG); aB = fmaf(w101, ub2(e[j][5]), aB);
            aR = fmaf(w110, ub0(e[j][6]), aR); aG = fmaf(w110, ub1(e[j][6]), aG); aB = fmaf(w110, ub2(e[j][6]), aB);
            aR = fmaf(w111, ub0(e[j][7]), aR); aG = fmaf(w111, ub1(e[j][7]), aG); aB = fmaf(w111, ub2(e[j][7]), aB);

            if (j < 4) { oRA[j] = aR;     oGA[j] = aG;     oBA[j] = aB; }
            else       { oRB[j - 4] = aR; oGB[j - 4] = aG; oBB[j - 4] = aB; }
        }

        // ---- Phase 4: fully-coalesced nontemporal stores (1KB/wave each).
        __builtin_nontemporal_store(oRA, (fvec4*)(out + base0));
        __builtin_nontemporal_store(oGA, (fvec4*)(out + base0 + P_PLANE));
        __builtin_nontemporal_store(oBA, (fvec4*)(out + base0 + 2 * P_PLANE));
        if (has2) {
            __builtin_nontemporal_store(oRB, (fvec4*)(out + base1));
            __builtin_nontemporal_store(oGB, (fvec4*)(out + base1 + P_PLANE));
            __builtin_nontemporal_store(oBB, (fvec4*)(out + base1 + 2 * P_PLANE));
        }
    }
}

// ===========================================================================
// Fallback path (R0, proven): fp16 cell-duplicated table + global gathers.
// ===========================================================================
__global__ __launch_bounds__(256) void build_table(const float* __restrict__ lut,
                                                   uint4* __restrict__ T) {
    int cell = blockIdx.x * blockDim.x + threadIdx.x;   // 0 .. 32767
    int rid = cell & 31;
    int gid = (cell >> 5) & 31;
    int bid = cell >> 10;
    const float* b0 = lut + bid * 1089 + gid * 33 + rid;
    uint4 q[4];
    __half* h = (__half*)q;
#pragma unroll
    for (int k = 0; k < 8; ++k) {
        int off = (k >> 2) * 1089 + ((k >> 1) & 1) * 33 + (k & 1);
        h[k * 4 + 0] = __float2half(b0[off]);
        h[k * 4 + 1] = __float2half(b0[LUT_C + off]);
        h[k * 4 + 2] = __float2half(b0[2 * LUT_C + off]);
        h[k * 4 + 3] = __float2half(0.0f);
    }
    uint4* dst = T + (size_t)cell * 4;
    dst[0] = q[0]; dst[1] = q[1]; dst[2] = q[2]; dst[3] = q[3];
}

__device__ __forceinline__ void acc_chunk(const uint4& q, float wA, float wB,
                                          float& aR, float& aG, float& aB) {
    const __half* h = (const __half*)&q;
    aR = fmaf(wA, __half2float(h[0]), fmaf(wB, __half2float(h[4]), aR));
    aG = fmaf(wA, __half2float(h[1]), fmaf(wB, __half2float(h[5]), aG));
    aB = fmaf(wA, __half2float(h[2]), fmaf(wB, __half2float(h[6]), aB));
}

__global__ __launch_bounds__(256) void apply_lut(const float* __restrict__ x,
                                                 const __half* __restrict__ T,
                                                 float* __restrict__ out) {
    const float inv = (float)(1.0 / (1.000001 / 32.0));
    int n  = blockIdx.y;
    int i4 = blockIdx.x * blockDim.x + threadIdx.x;
    size_t base = (size_t)n * 3 * P_PLANE + (size_t)i4 * 4;

    float4 r4 = *(const float4*)(x + base);
    float4 g4 = *(const float4*)(x + base + P_PLANE);
    float4 b4 = *(const float4*)(x + base + 2 * P_PLANE);

    float r[4] = {r4.x, r4.y, r4.z, r4.w};
    float g[4] = {g4.x, g4.y, g4.z, g4.w};
    float b[4] = {b4.x, b4.y, b4.z, b4.w};
    float oR[4], oG[4], oB[4];

#pragma unroll
    for (int i = 0; i < 4; ++i) {
        float tr = r[i] * inv;
        float tg = g[i] * inv;
        float tb = b[i] * inv;
        float fr_ = floorf(tr), fg_ = floorf(tg), fb_ = floorf(tb);
        float fr = tr - fr_, fg = tg - fg_, fb = tb - fb_;
        int ri = min(max((int)fr_, 0), 31);
        int gi = min(max((int)fg_, 0), 31);
        int bi = min(max((int)fb_, 0), 31);

        const uint4* cp = (const uint4*)(T + ((size_t)(((bi << 5) | gi) << 5 | ri) << 5));
        uint4 q0 = cp[0], q1 = cp[1], q2 = cp[2], q3 = cp[3];

        float wr1 = fr, wr0 = 1.0f - fr;
        float wg1 = fg, wg0 = 1.0f - fg;
        float wb1 = fb, wb0 = 1.0f - fb;
        float w00 = wb0 * wg0, w01 = wb0 * wg1, w10 = wb1 * wg0, w11 = wb1 * wg1;

        float aR = 0.f, aG = 0.f, aB = 0.f;
        acc_chunk(q0, w00 * wr0, w00 * wr1, aR, aG, aB);
        acc_chunk(q1, w01 * wr0, w01 * wr1, aR, aG, aB);
        acc_chunk(q2, w10 * wr0, w10 * wr1, aR, aG, aB);
        acc_chunk(q3, w11 * wr0, w11 * wr1, aR, aG, aB);

        oR[i] = aR; oG[i] = aG; oB[i] = aB;
    }

    *(float4*)(out + base)               = make_float4(oR[0], oR[1], oR[2], oR[3]);
    *(float4*)(out + base + P_PLANE)     = make_float4(oG[0], oG[1], oG[2], oG[3]);
    *(float4*)(out + base + 2 * P_PLANE) = make_float4(oB[0], oB[1], oB[2], oB[3]);
}

extern "C" void kernel_launch(void* const* d_in, const int* in_sizes, int n_in,
                              void* d_out, int out_size, void* d_ws, size_t ws_size,
                              hipStream_t stream) {
    const float* lut = (const float*)d_in[0];
    const float* x   = (const float*)d_in[1];
    float* out = (float*)d_out;

    // Capture-safe host-side queries — cached so repeated kernel_launch calls
    // don't pay the runtime-API cost per invocation.
    static int max_shm = -1;
    if (max_shm < 0) {
        int dev = 0;
        (void)hipGetDevice(&dev);
        (void)hipDeviceGetAttribute(&max_shm, hipDeviceAttributeMaxSharedMemoryPerBlock, dev);
        static_assert(SMEM_BYTES == 143748, "lut lds size");
        (void)hipFuncSetAttribute((const void*)apply_lut_lds,
                                  hipFuncAttributeMaxDynamicSharedMemorySize, SMEM_BYTES);
        if (max_shm < 0) max_shm = 0;
    }

    const size_t lin_bytes = (size_t)SMEM_BYTES;
    if (max_shm >= SMEM_BYTES && ws_size >= lin_bytes) {
        unsigned int* T = (unsigned int*)d_ws;
        build_lin_u8<<<(LUT_C + 255) / 256, 256, 0, stream>>>(lut, T);
        // 256 blocks x 1024 threads, 1 block/CU (LDS-bound); each thread owns
        // two grid-separated quads per iteration for 2x memory-level parallelism.
        apply_lut_lds<<<256, 1024, SMEM_BYTES, stream>>>(x, T, out);
    } else {
        __half* T = (__half*)d_ws;
        build_table<<<128, 256, 0, stream>>>(lut, (uint4*)T);
        apply_lut<<<dim3(P_PLANE / (4 * 256), N_IMG), 256, 0, stream>>>(x, T, out);
    }
}